// Round 1
// baseline (2809.827 us; speedup 1.0000x reference)
//
#include <hip/hip_runtime.h>

#define NS 50000
#define NI 100000
#define NT 150000
#define ANNZ 4800000
#define SNNZ 1000000
#define NBATCH 1024

struct __align__(8) Pair { int c; float v; };

// ---------------- CSR build ----------------

__global__ void hist_k(const int* __restrict__ rows, int nnz, int* __restrict__ cnt) {
    int stride = gridDim.x * blockDim.x;
    for (int i = blockIdx.x * blockDim.x + threadIdx.x; i < nnz; i += stride)
        atomicAdd(&cnt[rows[i]], 1);
}

__global__ __launch_bounds__(1024) void scan_k(const int* __restrict__ cnt, int n,
                                               int* __restrict__ rp) {
    __shared__ int sums[1024];
    int t = threadIdx.x;
    int chunk = (n + 1023) >> 10;
    int lo = t * chunk, hi = min(lo + chunk, n);
    int s = 0;
    for (int i = lo; i < hi; i++) s += cnt[i];
    sums[t] = s;
    __syncthreads();
    for (int off = 1; off < 1024; off <<= 1) {
        int v = sums[t];
        int u = (t >= off) ? sums[t - off] : 0;
        __syncthreads();
        sums[t] = v + u;
        __syncthreads();
    }
    int base = (t == 0) ? 0 : sums[t - 1];
    for (int i = lo; i < hi; i++) { rp[i] = base; base += cnt[i]; }
    if (t == 0) rp[n] = sums[1023];
}

__global__ void scatter_k(const int* __restrict__ rows, const int* __restrict__ cols,
                          const float* __restrict__ vals, int nnz,
                          const int* __restrict__ rp, int* __restrict__ fill,
                          Pair* __restrict__ pairs) {
    int stride = gridDim.x * blockDim.x;
    for (int i = blockIdx.x * blockDim.x + threadIdx.x; i < nnz; i += stride) {
        int r = rows[i];
        int pos = rp[r] + atomicAdd(&fill[r], 1);
        Pair p; p.c = cols[i]; p.v = vals[i];
        pairs[pos] = p;
    }
}

// ---------------- x_item copy (honors item_emb_idxes) ----------------

__global__ void embcopy_k(const int* __restrict__ idxs, const float* __restrict__ emb,
                          float* __restrict__ x) {
    int t = blockIdx.x * 256 + threadIdx.x;   // over NI*32 float4 chunks
    if (t >= NI * 32) return;
    int row = t >> 5, q = t & 31;
    int src = idxs[row];
    *(float4*)(x + (size_t)(NS + row) * 128 + q * 4) =
        *(const float4*)(emb + (size_t)src * 128 + q * 4);
}

// ---------------- SpMM: wave per CSR row ----------------
// WID: 2 -> 128 cols (float2/lane), 1 -> 64 cols (float/lane)

template <int WID, bool RELU>
__global__ __launch_bounds__(256) void spmm_k(const int* __restrict__ rp,
                                              const Pair* __restrict__ pairs,
                                              const float* __restrict__ x,
                                              const float* __restrict__ bias,
                                              float* __restrict__ y, int nrows) {
    int row = blockIdx.x * 4 + (threadIdx.x >> 6);
    if (row >= nrows) return;
    int lane = threadIdx.x & 63;
    constexpr int HO = WID * 64;
    int s = rp[row], e = rp[row + 1];
    if (WID == 2) {
        float a0 = 0.f, a1 = 0.f;
        int i = s;
        for (; i + 1 < e; i += 2) {
            Pair p0 = pairs[i], p1 = pairs[i + 1];
            float2 g0 = *(const float2*)(x + (size_t)p0.c * HO + 2 * lane);
            float2 g1 = *(const float2*)(x + (size_t)p1.c * HO + 2 * lane);
            a0 += p0.v * g0.x; a1 += p0.v * g0.y;
            a0 += p1.v * g1.x; a1 += p1.v * g1.y;
        }
        if (i < e) {
            Pair p = pairs[i];
            float2 g = *(const float2*)(x + (size_t)p.c * HO + 2 * lane);
            a0 += p.v * g.x; a1 += p.v * g.y;
        }
        if (bias) { a0 += bias[2 * lane]; a1 += bias[2 * lane + 1]; }
        if (RELU) { a0 = fmaxf(a0, 0.f); a1 = fmaxf(a1, 0.f); }
        float2 o; o.x = a0; o.y = a1;
        *(float2*)(y + (size_t)row * HO + 2 * lane) = o;
    } else {
        float a0 = 0.f;
        int i = s;
        for (; i + 1 < e; i += 2) {
            Pair p0 = pairs[i], p1 = pairs[i + 1];
            float g0 = x[(size_t)p0.c * HO + lane];
            float g1 = x[(size_t)p1.c * HO + lane];
            a0 += p0.v * g0 + p1.v * g1;
        }
        if (i < e) {
            Pair p = pairs[i];
            a0 += p.v * x[(size_t)p.c * HO + lane];
        }
        if (bias) a0 += bias[lane];
        if (RELU) a0 = fmaxf(a0, 0.f);
        y[(size_t)row * HO + lane] = a0;
    }
}

// ---------------- Dense GEMM: t[N,KOUT] = h[N,128] @ W[128,KOUT] ----------------

template <int KOUT, int TM>
__global__ __launch_bounds__(512) void gemm_k(const float* __restrict__ h,
                                              const float* __restrict__ W,
                                              float* __restrict__ t, int nrows) {
    constexpr int KIN = 128;
    constexpr int COLG = KOUT / 8;
    constexpr int ROWG = 512 / COLG;
    constexpr int ROWS = TM * ROWG;    // 128 in both configs
    __shared__ float hs[ROWS * KIN];
    __shared__ float ws[KIN * KOUT];
    int tid = threadIdx.x;
    int row0 = blockIdx.x * ROWS;
    // stage h tile (row-major, coalesced float4)
    for (int idx = tid; idx < ROWS * (KIN / 4); idx += 512) {
        int r = idx >> 5, kq = idx & 31;
        float4 v = make_float4(0.f, 0.f, 0.f, 0.f);
        int gr = row0 + r;
        if (gr < nrows) v = *(const float4*)(h + (size_t)gr * KIN + 4 * kq);
        *(float4*)&hs[r * KIN + 4 * kq] = v;
    }
    // stage W
    for (int idx = tid; idx < KIN * KOUT / 4; idx += 512)
        *(float4*)&ws[4 * idx] = *(const float4*)(W + 4 * idx);
    __syncthreads();
    int colg = tid % COLG, rowg = tid / COLG;
    int c0 = colg * 8, r0 = rowg * TM;
    float acc[TM][8];
#pragma unroll
    for (int j = 0; j < TM; j++)
#pragma unroll
        for (int c = 0; c < 8; c++) acc[j][c] = 0.f;
    for (int k = 0; k < KIN; k++) {
        float4 w0 = *(const float4*)&ws[k * KOUT + c0];
        float4 w1 = *(const float4*)&ws[k * KOUT + c0 + 4];
#pragma unroll
        for (int j = 0; j < TM; j++) {
            float xv = hs[(r0 + j) * KIN + k];
            acc[j][0] += xv * w0.x; acc[j][1] += xv * w0.y;
            acc[j][2] += xv * w0.z; acc[j][3] += xv * w0.w;
            acc[j][4] += xv * w1.x; acc[j][5] += xv * w1.y;
            acc[j][6] += xv * w1.z; acc[j][7] += xv * w1.w;
        }
    }
#pragma unroll
    for (int j = 0; j < TM; j++) {
        int gr = row0 + r0 + j;
        if (gr < nrows) {
            *(float4*)(t + (size_t)gr * KOUT + c0) =
                make_float4(acc[j][0], acc[j][1], acc[j][2], acc[j][3]);
            *(float4*)(t + (size_t)gr * KOUT + c0 + 4) =
                make_float4(acc[j][4], acc[j][5], acc[j][6], acc[j][7]);
        }
    }
}

// ---------------- Final: out[1024,100000] = h3[batch] @ h3[items]^T (K=64) -------

#define SPAD 132   // 128 sess + pad, 16B-aligned stride
#define IPAD 260   // 256 items + pad, 16B-aligned stride

__global__ __launch_bounds__(512) void out_k(const float* __restrict__ h3,
                                             const int* __restrict__ batch_idxes,
                                             const int* __restrict__ item_idxes,
                                             float* __restrict__ out) {
    __shared__ float sT[64 * SPAD];   // [k][s], 33.8 KB
    __shared__ float iT[64 * IPAD];   // [k][i], 66.6 KB
    int tid = threadIdx.x;
    int s_base = blockIdx.y * 128;
    int i_base = blockIdx.x * 256;
    // stage 128 sessions
    for (int idx = tid; idx < 128 * 16; idx += 512) {
        int s = idx >> 4, kq = idx & 15;
        int b = batch_idxes[s_base + s];
        float4 v = *(const float4*)(h3 + (size_t)b * 64 + 4 * kq);
        sT[(4 * kq + 0) * SPAD + s] = v.x;
        sT[(4 * kq + 1) * SPAD + s] = v.y;
        sT[(4 * kq + 2) * SPAD + s] = v.z;
        sT[(4 * kq + 3) * SPAD + s] = v.w;
    }
    // stage 256 items
    for (int idx = tid; idx < 256 * 16; idx += 512) {
        int i = idx >> 4, kq = idx & 15;
        int ig = i_base + i;
        float4 v = make_float4(0.f, 0.f, 0.f, 0.f);
        if (ig < NI) {
            int r = item_idxes[ig];
            v = *(const float4*)(h3 + (size_t)r * 64 + 4 * kq);
        }
        iT[(4 * kq + 0) * IPAD + i] = v.x;
        iT[(4 * kq + 1) * IPAD + i] = v.y;
        iT[(4 * kq + 2) * IPAD + i] = v.z;
        iT[(4 * kq + 3) * IPAD + i] = v.w;
    }
    __syncthreads();
    int ig_ = tid & 31, sg = tid >> 5;    // 16 sess-groups x 32 item-groups
    int s0 = sg * 8, i0 = ig_ * 8;
    float acc[8][8];
#pragma unroll
    for (int a = 0; a < 8; a++)
#pragma unroll
        for (int b = 0; b < 8; b++) acc[a][b] = 0.f;
    for (int k = 0; k < 64; k++) {
        float4 sa = *(const float4*)&sT[k * SPAD + s0];
        float4 sb = *(const float4*)&sT[k * SPAD + s0 + 4];
        float4 ia = *(const float4*)&iT[k * IPAD + i0];
        float4 ib = *(const float4*)&iT[k * IPAD + i0 + 4];
        float sv[8] = {sa.x, sa.y, sa.z, sa.w, sb.x, sb.y, sb.z, sb.w};
        float iv[8] = {ia.x, ia.y, ia.z, ia.w, ib.x, ib.y, ib.z, ib.w};
#pragma unroll
        for (int a = 0; a < 8; a++)
#pragma unroll
            for (int b = 0; b < 8; b++) acc[a][b] += sv[a] * iv[b];
    }
#pragma unroll
    for (int a = 0; a < 8; a++) {
        int srow = s_base + s0 + a;
        size_t o = (size_t)srow * NI + i_base + i0;
        if (i_base + i0 + 7 < NI) {
            *(float4*)(out + o)     = make_float4(acc[a][0], acc[a][1], acc[a][2], acc[a][3]);
            *(float4*)(out + o + 4) = make_float4(acc[a][4], acc[a][5], acc[a][6], acc[a][7]);
        } else {
            for (int b = 0; b < 8; b++)
                if (i_base + i0 + b < NI) out[o + b] = acc[a][b];
        }
    }
}

// ---------------- launch ----------------

extern "C" void kernel_launch(void* const* d_in, const int* in_sizes, int n_in,
                              void* d_out, int out_size, void* d_ws, size_t ws_size,
                              hipStream_t stream) {
    const int*   batch_idxes    = (const int*)d_in[0];
    const int*   A_rows         = (const int*)d_in[1];
    const int*   A_cols         = (const int*)d_in[2];
    const float* A_vals         = (const float*)d_in[3];
    const int*   item_idxes     = (const int*)d_in[4];
    const int*   sess_rows      = (const int*)d_in[5];
    const int*   sess_cols      = (const int*)d_in[6];
    const float* sess_vals      = (const float*)d_in[7];
    const int*   item_emb_idxes = (const int*)d_in[8];
    const float* emb            = (const float*)d_in[9];
    const float* W1 = (const float*)d_in[10]; const float* b1 = (const float*)d_in[11];
    const float* W2 = (const float*)d_in[12]; const float* b2 = (const float*)d_in[13];
    const float* W3 = (const float*)d_in[14]; const float* b3 = (const float*)d_in[15];
    float* out = (float*)d_out;

    char* ws = (char*)d_ws;
    size_t off = 0;
    auto alloc = [&](size_t bytes) -> char* {
        char* p = ws + off;
        off += (bytes + 255) & ~(size_t)255;
        return p;
    };
    float* buf0  = (float*)alloc((size_t)NT * 128 * 4);
    float* buf1  = (float*)alloc((size_t)NT * 128 * 4);
    int*   rpA   = (int*)alloc((size_t)(NT + 1) * 4);
    int*   cntA  = (int*)alloc((size_t)NT * 4);
    Pair*  pairsA = (Pair*)alloc((size_t)ANNZ * 8);
    int*   rpS   = (int*)alloc((size_t)(NS + 1) * 4);
    int*   cntS  = (int*)alloc((size_t)NS * 4);
    Pair*  pairsS = (Pair*)alloc((size_t)SNNZ * 8);

    // CSR build for A and session adjacency
    hipMemsetAsync(cntA, 0, (size_t)NT * 4, stream);
    hipMemsetAsync(cntS, 0, (size_t)NS * 4, stream);
    hist_k<<<1024, 256, 0, stream>>>(A_rows, ANNZ, cntA);
    hist_k<<<256, 256, 0, stream>>>(sess_rows, SNNZ, cntS);
    scan_k<<<1, 1024, 0, stream>>>(cntA, NT, rpA);
    scan_k<<<1, 1024, 0, stream>>>(cntS, NS, rpS);
    hipMemsetAsync(cntA, 0, (size_t)NT * 4, stream);
    hipMemsetAsync(cntS, 0, (size_t)NS * 4, stream);
    scatter_k<<<1024, 256, 0, stream>>>(A_rows, A_cols, A_vals, ANNZ, rpA, cntA, pairsA);
    scatter_k<<<256, 256, 0, stream>>>(sess_rows, sess_cols, sess_vals, SNNZ, rpS, cntS, pairsS);

    // x = [spmm(S, emb); emb]
    embcopy_k<<<(NI * 32 + 255) / 256, 256, 0, stream>>>(item_emb_idxes, emb, buf0);
    spmm_k<2, false><<<(NS + 3) / 4, 256, 0, stream>>>(rpS, pairsS,
        buf0 + (size_t)NS * 128, nullptr, buf0, NS);

    // layer 1
    gemm_k<128, 4><<<(NT + 127) / 128, 512, 0, stream>>>(buf0, W1, buf1, NT);
    spmm_k<2, true><<<(NT + 3) / 4, 256, 0, stream>>>(rpA, pairsA, buf1, b1, buf0, NT);
    // layer 2
    gemm_k<128, 4><<<(NT + 127) / 128, 512, 0, stream>>>(buf0, W2, buf1, NT);
    spmm_k<2, true><<<(NT + 3) / 4, 256, 0, stream>>>(rpA, pairsA, buf1, b2, buf0, NT);
    // layer 3 (no relu)
    gemm_k<64, 2><<<(NT + 127) / 128, 512, 0, stream>>>(buf0, W3, buf1, NT);
    spmm_k<1, false><<<(NT + 3) / 4, 256, 0, stream>>>(rpA, pairsA, buf1, b3, buf0, NT);

    // scoring
    dim3 og((NI + 255) / 256, NBATCH / 128);
    out_k<<<og, 512, 0, stream>>>(buf0, batch_idxes, item_idxes, out);
}

// Round 2
// 2698.797 us; speedup vs baseline: 1.0411x; 1.0411x over previous
//
#include <hip/hip_runtime.h>

#define NS 50000
#define NI 100000
#define NT 150000
#define ANNZ 4800000
#define SNNZ 1000000
#define NBATCH 1024

struct __align__(8) Pair { int c; float v; };

// ---------------- CSR build ----------------

__global__ void hist_k(const int* __restrict__ rows, int nnz, int* __restrict__ cnt) {
    int stride = gridDim.x * blockDim.x;
    for (int i = blockIdx.x * blockDim.x + threadIdx.x; i < nnz; i += stride)
        atomicAdd(&cnt[rows[i]], 1);
}

__global__ __launch_bounds__(1024) void scan_k(const int* __restrict__ cnt, int n,
                                               int* __restrict__ rp) {
    __shared__ int sums[1024];
    int t = threadIdx.x;
    int chunk = (n + 1023) >> 10;
    int lo = t * chunk, hi = min(lo + chunk, n);
    int s = 0;
    for (int i = lo; i < hi; i++) s += cnt[i];
    sums[t] = s;
    __syncthreads();
    for (int off = 1; off < 1024; off <<= 1) {
        int v = sums[t];
        int u = (t >= off) ? sums[t - off] : 0;
        __syncthreads();
        sums[t] = v + u;
        __syncthreads();
    }
    int base = (t == 0) ? 0 : sums[t - 1];
    for (int i = lo; i < hi; i++) { rp[i] = base; base += cnt[i]; }
    if (t == 0) rp[n] = sums[1023];
}

__global__ void scatter_k(const int* __restrict__ rows, const int* __restrict__ cols,
                          const float* __restrict__ vals, int nnz,
                          const int* __restrict__ rp, int* __restrict__ fill,
                          Pair* __restrict__ pairs) {
    int stride = gridDim.x * blockDim.x;
    for (int i = blockIdx.x * blockDim.x + threadIdx.x; i < nnz; i += stride) {
        int r = rows[i];
        int pos = rp[r] + atomicAdd(&fill[r], 1);
        Pair p; p.c = cols[i]; p.v = vals[i];
        pairs[pos] = p;
    }
}

// ---------------- SpMM 128-wide: half-wave per nnz, float4/lane ----------------

__device__ __forceinline__ Pair ldpair_nt(const Pair* p) {
    long long raw = __builtin_nontemporal_load((const long long*)p);
    return __builtin_bit_cast(Pair, raw);
}

template <bool RELU>
__global__ __launch_bounds__(256) void spmm128_k(const int* __restrict__ rp,
                                                 const Pair* __restrict__ pairs,
                                                 const float* __restrict__ x,
                                                 const float* __restrict__ bias,
                                                 float* __restrict__ y, int nrows) {
    int r = blockIdx.x * 4 + (threadIdx.x >> 6);
    if (r >= nrows) return;
    int lane = threadIdx.x & 63;
    int half = lane >> 5, q = lane & 31;
    int s = rp[r], e = rp[r + 1];
    float4 acc = make_float4(0.f, 0.f, 0.f, 0.f);
    int i = s;
    for (; i + 3 < e; i += 4) {
        Pair pa = ldpair_nt(pairs + i + half);
        Pair pb = ldpair_nt(pairs + i + 2 + half);
        float4 ga = *((const float4*)(x + (size_t)pa.c * 128) + q);
        float4 gb = *((const float4*)(x + (size_t)pb.c * 128) + q);
        acc.x += pa.v * ga.x + pb.v * gb.x;
        acc.y += pa.v * ga.y + pb.v * gb.y;
        acc.z += pa.v * ga.z + pb.v * gb.z;
        acc.w += pa.v * ga.w + pb.v * gb.w;
    }
    for (; i + 1 < e; i += 2) {
        Pair p = ldpair_nt(pairs + i + half);
        float4 g = *((const float4*)(x + (size_t)p.c * 128) + q);
        acc.x += p.v * g.x; acc.y += p.v * g.y;
        acc.z += p.v * g.z; acc.w += p.v * g.w;
    }
    if (i < e && half == 0) {
        Pair p = ldpair_nt(pairs + i);
        float4 g = *((const float4*)(x + (size_t)p.c * 128) + q);
        acc.x += p.v * g.x; acc.y += p.v * g.y;
        acc.z += p.v * g.z; acc.w += p.v * g.w;
    }
    acc.x += __shfl_xor(acc.x, 32);
    acc.y += __shfl_xor(acc.y, 32);
    acc.z += __shfl_xor(acc.z, 32);
    acc.w += __shfl_xor(acc.w, 32);
    if (half == 0) {
        if (bias) {
            float4 b = *((const float4*)bias + q);
            acc.x += b.x; acc.y += b.y; acc.z += b.z; acc.w += b.w;
        }
        if (RELU) {
            acc.x = fmaxf(acc.x, 0.f); acc.y = fmaxf(acc.y, 0.f);
            acc.z = fmaxf(acc.z, 0.f); acc.w = fmaxf(acc.w, 0.f);
        }
        *((float4*)(y + (size_t)r * 128) + q) = acc;
    }
}

// ---------------- SpMM 64-wide: quarter-wave per nnz, float4/lane --------------

__global__ __launch_bounds__(256) void spmm64_k(const int* __restrict__ rp,
                                                const Pair* __restrict__ pairs,
                                                const float* __restrict__ x,
                                                const float* __restrict__ bias,
                                                float* __restrict__ y, int nrows,
                                                int row_off,
                                                const int* __restrict__ row_map) {
    int r = blockIdx.x * 4 + (threadIdx.x >> 6);
    if (r >= nrows) return;
    int csr = row_map ? row_map[r] : row_off + r;
    int lane = threadIdx.x & 63;
    int quar = lane >> 4, q = lane & 15;
    int s = rp[csr], e = rp[csr + 1];
    float4 acc = make_float4(0.f, 0.f, 0.f, 0.f);
    int i = s;
    for (; i + 3 < e; i += 4) {
        Pair p = ldpair_nt(pairs + i + quar);
        float4 g = *((const float4*)(x + (size_t)p.c * 64) + q);
        acc.x += p.v * g.x; acc.y += p.v * g.y;
        acc.z += p.v * g.z; acc.w += p.v * g.w;
    }
    if (i < e) {
        int rem = e - i;                       // 1..3
        Pair p = ldpair_nt(pairs + i + min(quar, rem - 1));
        float v = (quar < rem) ? p.v : 0.f;
        float4 g = *((const float4*)(x + (size_t)p.c * 64) + q);
        acc.x += v * g.x; acc.y += v * g.y;
        acc.z += v * g.z; acc.w += v * g.w;
    }
    acc.x += __shfl_xor(acc.x, 16); acc.y += __shfl_xor(acc.y, 16);
    acc.z += __shfl_xor(acc.z, 16); acc.w += __shfl_xor(acc.w, 16);
    acc.x += __shfl_xor(acc.x, 32); acc.y += __shfl_xor(acc.y, 32);
    acc.z += __shfl_xor(acc.z, 32); acc.w += __shfl_xor(acc.w, 32);
    if (quar == 0) {
        if (bias) {
            float4 b = *((const float4*)bias + q);
            acc.x += b.x; acc.y += b.y; acc.z += b.z; acc.w += b.w;
        }
        *((float4*)(y + (size_t)r * 64) + q) = acc;
    }
}

// ---------------- Dense GEMM: t[dst_off+r] = h[gidx?gidx[r]:r] @ W ------------
// Conflict-free: hs padded stride 132; ws read as strided scalars.

template <int KOUT, int TM, int COLG>
__global__ __launch_bounds__(512) void gemm_k(const float* __restrict__ h,
                                              const float* __restrict__ W,
                                              float* __restrict__ t, int nrows,
                                              const int* __restrict__ gidx,
                                              int dst_off) {
    constexpr int KIN = 128;
    constexpr int ROWS = 128;
    constexpr int HSP = 132;
    __shared__ float hs[ROWS * HSP];
    __shared__ float ws[KIN * KOUT];
    int tid = threadIdx.x;
    int row0 = blockIdx.x * ROWS;
    for (int idx = tid; idx < ROWS * 32; idx += 512) {
        int r = idx >> 5, kq = idx & 31;
        float4 v = make_float4(0.f, 0.f, 0.f, 0.f);
        int gr = row0 + r;
        if (gr < nrows) {
            int sr = gidx ? gidx[gr] : gr;
            v = *((const float4*)(h + (size_t)sr * KIN) + kq);
        }
        *(float4*)&hs[r * HSP + 4 * kq] = v;
    }
    for (int idx = tid; idx < KIN * KOUT / 4; idx += 512)
        *(float4*)&ws[4 * idx] = *((const float4*)W + idx);
    __syncthreads();
    int colg = tid % COLG, rowg = tid / COLG;
    int r0 = rowg * TM;
    float acc[TM][8];
#pragma unroll
    for (int j = 0; j < TM; j++)
#pragma unroll
        for (int m = 0; m < 8; m++) acc[j][m] = 0.f;
    for (int k = 0; k < KIN; k++) {
        float wv[8];
#pragma unroll
        for (int m = 0; m < 8; m++) wv[m] = ws[k * KOUT + colg + COLG * m];
        float hv[TM];
#pragma unroll
        for (int j = 0; j < TM; j++) hv[j] = hs[(r0 + j) * HSP + k];
#pragma unroll
        for (int j = 0; j < TM; j++)
#pragma unroll
            for (int m = 0; m < 8; m++) acc[j][m] += hv[j] * wv[m];
    }
#pragma unroll
    for (int j = 0; j < TM; j++) {
        int gr = row0 + r0 + j;
        if (gr < nrows) {
            float* o = t + (size_t)(dst_off + gr) * KOUT;
#pragma unroll
            for (int m = 0; m < 8; m++) o[colg + COLG * m] = acc[j][m];
        }
    }
}

// ---------------- Final scoring: out[1024,NI] = h3s @ h3i^T (K=64) ------------

#define SPAD 132
#define IPAD 258

__global__ __launch_bounds__(512) void out_k(const float* __restrict__ h3s,
                                             const float* __restrict__ h3i,
                                             const int* __restrict__ item_idxes,
                                             float* __restrict__ out) {
    __shared__ float sT[64 * SPAD];
    __shared__ float iT[64 * IPAD];
    int tid = threadIdx.x;
    int s_base = blockIdx.y * 128;
    int i_base = blockIdx.x * 256;
    for (int idx = tid; idx < 128 * 16; idx += 512) {
        int s = idx >> 4, kq = idx & 15;
        float4 v = *((const float4*)(h3s + (size_t)(s_base + s) * 64) + kq);
        sT[(4 * kq + 0) * SPAD + s] = v.x;
        sT[(4 * kq + 1) * SPAD + s] = v.y;
        sT[(4 * kq + 2) * SPAD + s] = v.z;
        sT[(4 * kq + 3) * SPAD + s] = v.w;
    }
    for (int idx = tid; idx < 256 * 16; idx += 512) {
        int i = idx >> 4, kq = idx & 15;
        int ig = i_base + i;
        float4 v = make_float4(0.f, 0.f, 0.f, 0.f);
        if (ig < NI) {
            int rr = item_idxes[ig] - NS;
            v = *((const float4*)(h3i + (size_t)rr * 64) + kq);
        }
        iT[(4 * kq + 0) * IPAD + i] = v.x;
        iT[(4 * kq + 1) * IPAD + i] = v.y;
        iT[(4 * kq + 2) * IPAD + i] = v.z;
        iT[(4 * kq + 3) * IPAD + i] = v.w;
    }
    __syncthreads();
    int il = tid & 31, sg = tid >> 5;
    int s0 = sg * 8;
    float acc[8][8];
#pragma unroll
    for (int a = 0; a < 8; a++)
#pragma unroll
        for (int b = 0; b < 8; b++) acc[a][b] = 0.f;
    for (int k = 0; k < 64; k++) {
        float4 sa = *(const float4*)&sT[k * SPAD + s0];
        float4 sb = *(const float4*)&sT[k * SPAD + s0 + 4];
        float sv[8] = {sa.x, sa.y, sa.z, sa.w, sb.x, sb.y, sb.z, sb.w};
        float2 iv[4];
#pragma unroll
        for (int m = 0; m < 4; m++)
            iv[m] = *(const float2*)&iT[k * IPAD + il * 2 + 64 * m];
#pragma unroll
        for (int a = 0; a < 8; a++)
#pragma unroll
            for (int m = 0; m < 4; m++) {
                acc[a][2 * m]     += sv[a] * iv[m].x;
                acc[a][2 * m + 1] += sv[a] * iv[m].y;
            }
    }
#pragma unroll
    for (int a = 0; a < 8; a++) {
        int srow = s_base + s0 + a;
        size_t ob = (size_t)srow * NI + i_base;
#pragma unroll
        for (int m = 0; m < 4; m++) {
            int loc = il * 2 + 64 * m;
            int ii = i_base + loc;
            if (ii + 1 < NI) {
                float2 v2 = make_float2(acc[a][2 * m], acc[a][2 * m + 1]);
                __builtin_nontemporal_store(__builtin_bit_cast(double, v2),
                                            (double*)(out + ob + loc));
            } else if (ii < NI) {
                out[ob + loc] = acc[a][2 * m];
            }
        }
    }
}

// ---------------- launch ----------------

extern "C" void kernel_launch(void* const* d_in, const int* in_sizes, int n_in,
                              void* d_out, int out_size, void* d_ws, size_t ws_size,
                              hipStream_t stream) {
    const int*   batch_idxes    = (const int*)d_in[0];
    const int*   A_rows         = (const int*)d_in[1];
    const int*   A_cols         = (const int*)d_in[2];
    const float* A_vals         = (const float*)d_in[3];
    const int*   item_idxes     = (const int*)d_in[4];
    const int*   sess_rows      = (const int*)d_in[5];
    const int*   sess_cols      = (const int*)d_in[6];
    const float* sess_vals      = (const float*)d_in[7];
    const int*   item_emb_idxes = (const int*)d_in[8];
    const float* emb            = (const float*)d_in[9];
    const float* W1 = (const float*)d_in[10]; const float* b1 = (const float*)d_in[11];
    const float* W2 = (const float*)d_in[12]; const float* b2 = (const float*)d_in[13];
    const float* W3 = (const float*)d_in[14]; const float* b3 = (const float*)d_in[15];
    float* out = (float*)d_out;

    char* ws = (char*)d_ws;
    size_t off = 0;
    auto alloc = [&](size_t bytes) -> char* {
        char* p = ws + off;
        off += (bytes + 255) & ~(size_t)255;
        return p;
    };
    float* bufA  = (float*)alloc((size_t)NT * 128 * 4);   // t buffers
    float* bufB  = (float*)alloc((size_t)NT * 128 * 4);   // h buffers
    int*   rpA   = (int*)alloc((size_t)(NT + 1) * 4);
    int*   cntA  = (int*)alloc((size_t)NT * 4);
    Pair*  pairsA = (Pair*)alloc((size_t)ANNZ * 8);
    int*   rpS   = (int*)alloc((size_t)(NS + 1) * 4);
    int*   cntS  = (int*)alloc((size_t)NS * 4);
    Pair*  pairsS = (Pair*)alloc((size_t)SNNZ * 8);

    // h3 buffers alias bufB (h2 is dead once gemm3 has produced t3 in bufA)
    float* h3i = bufB;                       // [NI,64]
    float* h3s = bufB + (size_t)NI * 64;     // [1024,64]

    // CSR build
    hipMemsetAsync(cntA, 0, (size_t)NT * 4, stream);
    hipMemsetAsync(cntS, 0, (size_t)NS * 4, stream);
    hist_k<<<1024, 256, 0, stream>>>(A_rows, ANNZ, cntA);
    hist_k<<<256, 256, 0, stream>>>(sess_rows, SNNZ, cntS);
    scan_k<<<1, 1024, 0, stream>>>(cntA, NT, rpA);
    scan_k<<<1, 1024, 0, stream>>>(cntS, NS, rpS);
    hipMemsetAsync(cntA, 0, (size_t)NT * 4, stream);
    hipMemsetAsync(cntS, 0, (size_t)NS * 4, stream);
    scatter_k<<<1024, 256, 0, stream>>>(A_rows, A_cols, A_vals, ANNZ, rpA, cntA, pairsA);
    scatter_k<<<256, 256, 0, stream>>>(sess_rows, sess_cols, sess_vals, SNNZ, rpS, cntS, pairsS);

    // t1 = [S@(emb@W1) ; emb@W1]  (associativity: (S@emb)@W1 = S@(emb@W1))
    gemm_k<128, 4, 16><<<(NI + 127) / 128, 512, 0, stream>>>(
        emb, W1, bufA, NI, item_emb_idxes, NS);
    spmm128_k<false><<<(NS + 3) / 4, 256, 0, stream>>>(
        rpS, pairsS, bufA + (size_t)NS * 128, nullptr, bufA, NS);
    // h1 = relu(A@t1 + b1)
    spmm128_k<true><<<(NT + 3) / 4, 256, 0, stream>>>(rpA, pairsA, bufA, b1, bufB, NT);
    // layer 2
    gemm_k<128, 4, 16><<<(NT + 127) / 128, 512, 0, stream>>>(bufB, W2, bufA, NT, nullptr, 0);
    spmm128_k<true><<<(NT + 3) / 4, 256, 0, stream>>>(rpA, pairsA, bufA, b2, bufB, NT);
    // layer 3: t3 = h2@W3 (all rows), h3 only at item rows + batch rows
    gemm_k<64, 2, 8><<<(NT + 127) / 128, 512, 0, stream>>>(bufB, W3, bufA, NT, nullptr, 0);
    spmm64_k<<<(NI + 3) / 4, 256, 0, stream>>>(rpA, pairsA, bufA, b3, h3i, NI, NS, nullptr);
    spmm64_k<<<(NBATCH + 3) / 4, 256, 0, stream>>>(rpA, pairsA, bufA, b3, h3s, NBATCH, 0, batch_idxes);

    // scoring
    dim3 og((NI + 255) / 256, NBATCH / 128);
    out_k<<<og, 512, 0, stream>>>(h3s, h3i, item_idxes, out);
}